// Round 12
// baseline (182.935 us; speedup 1.0000x reference)
//
#include <hip/hip_runtime.h>
#include <stdint.h>

// Problem constants
#define NB   32768
#define SS   11
#define DD   128
#define HH   32
#define ROWS (NB * SS)            // 360448
#define BPB  23                   // whole batches per block (23*11 = 253 <= 256)
#define TPB  256
#define NBLK ((NB + BPB - 1) / BPB)   // 1425
#define TOT4 (ROWS * SS / 4)      // 991232 float4 of attn ones
#define NTHR (NBLK * TPB)         // 364800

// One block, 256 threads. aux[0..64) = M = Wv@Wo (layout [j][o]);
// aux[64..86) = posW[t][o] = bo[o] + sum_{u in win(t)} (pos[u] @ M)[o]
__global__ __launch_bounds__(256) void setup_kernel(
    const float* __restrict__ Wv, const float* __restrict__ Wo,
    const float* __restrict__ pos, const float* __restrict__ bo,
    float* __restrict__ aux)
{
    __shared__ float M_s[HH * 2];
    __shared__ float pm_s[SS * 2];
    const int t = threadIdx.x;
    {   // thread (j, o, kq): 4-way k-split, shfl-reduce over kq (lane bits 0-1)
        int i2 = t >> 2, kq = t & 3;
        int j = i2 >> 1, o = i2 & 1;
        float s = 0.f;
        #pragma unroll
        for (int k = kq * 8; k < kq * 8 + 8; ++k)
            s += Wv[j * HH + k] * Wo[k * 2 + o];
        s += __shfl_xor(s, 1);
        s += __shfl_xor(s, 2);
        if (kq == 0) { M_s[i2] = s; aux[i2] = s; }
    }
    __syncthreads();
    if (t < 2 * SS) {
        int u = t >> 1, o = t & 1;
        float s = 0.f;
        #pragma unroll 8
        for (int j = 0; j < HH; ++j) s += pos[u * HH + j] * M_s[j * 2 + o];
        pm_s[t] = s;
    }
    __syncthreads();
    if (t < 2 * SS) {
        int tt = t >> 1, o = t & 1;
        int lo = tt - 5 < 0 ? 0 : tt - 5;
        int hi = tt + 5 > SS - 1 ? SS - 1 : tt + 5;
        float s = bo[o];
        for (int u = lo; u <= hi; ++u) s += pm_s[u * 2 + o];
        aux[64 + t] = s;
    }
}

// One thread = one (b,t) row. All-f32:
//   g_r = relu(x_r @ W1 + b1) @ M          (W1/b1/M are wave-uniform -> s_load)
//   out1[b,t] = posW[t] + sum_{u in win(t)} g_{b,u}   (block-local via 2KB LDS)
// Plus attn-ones fill folded in. No staging, no phase-lock, streaming HBM.
__global__ __launch_bounds__(256) void fused_kernel(
    const float* __restrict__ x, const float* __restrict__ W1,
    const float* __restrict__ b1, const float* __restrict__ aux,
    float* __restrict__ out1, float4* __restrict__ attn, int ones_lim)
{
    __shared__ float2 gsh[256];

    const int t = threadIdx.x, blk = blockIdx.x;
    const int lb = t / SS, tt = t - lb * SS;   // local batch, seq pos
    const int bq = blk * BPB + lb;             // global batch
    const bool active = (lb < BPB) & (bq < NB);
    const int r = bq * SS + tt;                // global row

    if (active) {
        float acc[HH];
        #pragma unroll
        for (int j = 0; j < HH; ++j) acc[j] = 0.f;

        const float* __restrict__ xr = x + (size_t)r * DD;
        for (int d4 = 0; d4 < 32; ++d4) {      // stream own row, 16B chunks
            float4 xv = *(const float4*)(xr + d4 * 4);
            const float* __restrict__ w0 = W1 + (d4 * 4) * HH;
            #pragma unroll
            for (int j = 0; j < HH; ++j) acc[j] = fmaf(xv.x, w0[j], acc[j]);
            #pragma unroll
            for (int j = 0; j < HH; ++j) acc[j] = fmaf(xv.y, w0[HH + j], acc[j]);
            #pragma unroll
            for (int j = 0; j < HH; ++j) acc[j] = fmaf(xv.z, w0[2 * HH + j], acc[j]);
            #pragma unroll
            for (int j = 0; j < HH; ++j) acc[j] = fmaf(xv.w, w0[3 * HH + j], acc[j]);
        }
        float s0 = 0.f, s1 = 0.f;
        #pragma unroll
        for (int j = 0; j < HH; ++j) {
            float y = fmaxf(acc[j] + b1[j], 0.f);   // b1, aux: uniform -> s_load
            s0 = fmaf(y, aux[j * 2], s0);
            s1 = fmaf(y, aux[j * 2 + 1], s1);
        }
        gsh[t] = make_float2(s0, s1);
    }
    __syncthreads();
    if (active) {
        int lo = tt - 5 < 0 ? 0 : tt - 5;
        int hi = tt + 5 > SS - 1 ? SS - 1 : tt + 5;
        float2 pw = *(const float2*)&aux[64 + tt * 2];
        float s0 = pw.x, s1 = pw.y;
        int base = lb * SS;
        for (int u = lo; u <= hi; ++u) {
            float2 v = gsh[base + u];
            s0 += v.x; s1 += v.y;
        }
        ((float2*)out1)[r] = make_float2(s0, s1);
    }
    // ---- attn_w == 1.0 fill (3 strided writes covers 991232 float4) ----
    const int idx = blk * TPB + t;
    #pragma unroll
    for (int i = 0; i < 3; ++i) {
        int k = idx + i * NTHR;
        if (k < ones_lim) attn[k] = make_float4(1.f, 1.f, 1.f, 1.f);
    }
}

// fallback-only: aux lived in the last 128 floats of attn; fix them to 1.0
__global__ void ones_tail_kernel(float4* __restrict__ p)
{
    p[TOT4 - 32 + threadIdx.x] = make_float4(1.f, 1.f, 1.f, 1.f);
}

extern "C" void kernel_launch(void* const* d_in, const int* in_sizes, int n_in,
                              void* d_out, int out_size, void* d_ws, size_t ws_size,
                              hipStream_t stream)
{
    const float* x   = (const float*)d_in[0];
    const float* W1  = (const float*)d_in[1];
    const float* b1  = (const float*)d_in[2];
    // d_in[3] = Wq, d_in[4] = Wk: dead (softmax over singleton dim -> attn_w == 1)
    const float* Wv  = (const float*)d_in[5];
    const float* pos = (const float*)d_in[6];
    const float* Wo  = (const float*)d_in[7];
    const float* bo  = (const float*)d_in[8];

    float* out1 = (float*)d_out;                 // (B,S,2)
    float* attn = out1 + (size_t)ROWS * 2;       // (B,S,1,11) = TOT4 float4

    const bool ws_ok = ws_size >= 128 * sizeof(float);
    // aux = 86 floats (M[64] + posW[22]); fallback: last 128 floats of attn,
    // which fused_kernel then leaves untouched (ones_lim) and a tail fixes up.
    float* aux = ws_ok ? (float*)d_ws : (attn + (size_t)(TOT4 - 32) * 4);
    const int ones_lim = ws_ok ? TOT4 : TOT4 - 32;

    setup_kernel<<<1, 256, 0, stream>>>(Wv, Wo, pos, bo, aux);
    fused_kernel<<<NBLK, TPB, 0, stream>>>(x, W1, b1, aux, out1,
                                           (float4*)attn, ones_lim);
    if (!ws_ok)
        ones_tail_kernel<<<1, 32, 0, stream>>>((float4*)attn);
}